// Round 3
// baseline (1897.080 us; speedup 1.0000x reference)
//
#include <hip/hip_runtime.h>

#define THREADS 256
#define BSH 7
#define BN  128                 // nodes per bucket
#define NBMAX 1024              // max buckets (n <= 131072)

// ---------------- binning ----------------
__global__ __launch_bounds__(1024) void k_zerob(int* __restrict__ bcnt) {
    bcnt[threadIdx.x] = 0;
}

__global__ __launch_bounds__(THREADS) void k_binhist(const int* __restrict__ dst,
                                                     int* __restrict__ bcnt,
                                                     int E, int nb) {
    __shared__ int h[NBMAX];
    for (int i = threadIdx.x; i < NBMAX; i += THREADS) h[i] = 0;
    __syncthreads();
    for (int e = blockIdx.x * THREADS + threadIdx.x; e < E; e += gridDim.x * THREADS)
        atomicAdd(&h[dst[e] >> BSH], 1);
    __syncthreads();
    for (int i = threadIdx.x; i < nb; i += THREADS) {
        int v = h[i];
        if (v) atomicAdd(&bcnt[i], v);
    }
}

__global__ __launch_bounds__(1024) void k_binscan(const int* __restrict__ bcnt,
                                                  int* __restrict__ boff,
                                                  int* __restrict__ bwp, int nb) {
    __shared__ int s[1024];
    const int tid = threadIdx.x;
    int v = (tid < nb) ? bcnt[tid] : 0;
    int a = v;
    s[tid] = a; __syncthreads();
    for (int d = 1; d < 1024; d <<= 1) {
        int add = (tid >= d) ? s[tid - d] : 0;
        __syncthreads();
        a += add; s[tid] = a;
        __syncthreads();
    }
    if (tid < nb) { boff[tid] = a - v; bwp[tid] = a - v; }
}

__global__ __launch_bounds__(THREADS) void k_binfill(const int* __restrict__ src,
                                                     const int* __restrict__ dst,
                                                     int* __restrict__ bwp,
                                                     int* __restrict__ ebuf, int E) {
    for (int e = blockIdx.x * THREADS + threadIdx.x; e < E; e += gridDim.x * THREADS) {
        int d = dst[e];
        int pos = atomicAdd(&bwp[d >> BSH], 1);
        ebuf[pos] = (src[e] << BSH) | (d & (BN - 1));
    }
}

// ---------------- degree -> dinv (per-bucket LDS histogram) ----------------
__global__ __launch_bounds__(THREADS) void k_deg(const int* __restrict__ ebuf,
                                                 const int* __restrict__ boff,
                                                 const int* __restrict__ bcnt,
                                                 float* __restrict__ dinv, int n) {
    __shared__ int h[BN];
    const int b = blockIdx.x, t = threadIdx.x;
    if (t < BN) h[t] = 0;
    __syncthreads();
    const int beg = boff[b], m = bcnt[b];
    for (int j = t; j < m; j += THREADS)
        atomicAdd(&h[ebuf[beg + j] & (BN - 1)], 1);
    __syncthreads();
    if (t < BN) {
        int node = (b << BSH) + t;
        if (node < n) dinv[node] = rsqrtf((float)h[t] + 1.0f);  // +1 self loop
    }
}

// ---------------- GEMM1: xw[i][f] = (x[i] @ W1)[f] * dinv[i] ----------------
__global__ __launch_bounds__(THREADS) void k_gemm1(const float* __restrict__ x,
                                                   const float* __restrict__ W1,
                                                   const float* __restrict__ dinv,
                                                   float* __restrict__ xw, int n) {
    __shared__ float xs[16 * 292];
    __shared__ float wsh[288 * 16];
    const int t = threadIdx.x;
    const int block0 = blockIdx.x * 16;

    for (int i = t; i < 288 * 16; i += THREADS) wsh[i] = W1[i];

    int rows = n - block0; if (rows > 16) rows = 16;
    const float4* x4 = reinterpret_cast<const float4*>(x + (size_t)block0 * 288);
    const int tot4 = rows * 72;
    for (int i = t; i < tot4; i += THREADS) {
        int r = i / 72, c = i - r * 72;
        *reinterpret_cast<float4*>(&xs[r * 292 + c * 4]) = x4[i];
    }
    __syncthreads();

    const int nl = t >> 4, f = t & 15;
    const int row = block0 + nl;
    if (row < n) {
        float acc = 0.f;
        #pragma unroll 8
        for (int k = 0; k < 288; ++k)
            acc = fmaf(xs[nl * 292 + k], wsh[k * 16 + f], acc);
        xw[(size_t)row * 16 + f] = acc * dinv[row];
    }
}

// ---------------- binned LDS push aggregation ----------------
// xws rows pre-scaled by dinv[src]; self-loop = own row; final * dinv[node].
template <int F>
__global__ __launch_bounds__(THREADS) void k_agg(const float* __restrict__ xws,
                                                 const int* __restrict__ ebuf,
                                                 const int* __restrict__ boff,
                                                 const int* __restrict__ bcnt,
                                                 const float* __restrict__ dinv,
                                                 float* __restrict__ out, int n) {
    __shared__ float acc[BN * F];
    const int b = blockIdx.x, t = threadIdx.x;
    const int base = b << BSH;
    constexpr int EP = THREADS / F;        // entries per iteration
    const int f = t % F, r0 = t / F;

    for (int rr = r0; rr < BN; rr += EP) {
        int node = base + rr;
        acc[rr * F + f] = (node < n) ? xws[(size_t)node * F + f] : 0.f;  // self
    }
    __syncthreads();

    const int beg = boff[b], m = bcnt[b];
    #pragma unroll 4
    for (int j = r0; j < m; j += EP) {
        int ent = ebuf[beg + j];
        int s = ent >> BSH, dl = ent & (BN - 1);
        atomicAdd(&acc[dl * F + f], xws[(size_t)s * F + f]);
    }
    __syncthreads();

    for (int rr = r0; rr < BN; rr += EP) {
        int node = base + rr;
        if (node < n) out[(size_t)node * F + f] = acc[rr * F + f] * dinv[node];
    }
}

// ---------------- GEMM2: h[i][f] = relu(agg1[i] + b1) @ W2 * dinv[i] ----------------
__global__ __launch_bounds__(THREADS) void k_gemm2(const float* __restrict__ agg1,
                                                   const float* __restrict__ b1,
                                                   const float* __restrict__ W2,
                                                   const float* __restrict__ dinv,
                                                   float* __restrict__ h, int n) {
    int t = blockIdx.x * THREADS + threadIdx.x;
    if (t >= n * 32) return;
    int node = t >> 5, f = t & 31;
    const float* row = agg1 + (size_t)node * 16;
    float acc = 0.f;
    #pragma unroll
    for (int k = 0; k < 16; ++k) {
        float v = fmaxf(row[k] + b1[k], 0.f);
        acc = fmaf(v, W2[k * 32 + f], acc);
    }
    h[t] = acc * dinv[node];
}

// ---------------- final FC ----------------
__global__ __launch_bounds__(THREADS) void k_final(const float* __restrict__ agg2,
                                                   const float* __restrict__ b2,
                                                   const float* __restrict__ Wfc,
                                                   const float* __restrict__ bfc,
                                                   float* __restrict__ out, int n) {
    int t = blockIdx.x * THREADS + threadIdx.x;
    if (t >= n * 7) return;
    int node = t / 7, o = t - node * 7;
    const float* row = agg2 + (size_t)node * 32;
    float acc = bfc[o];
    #pragma unroll
    for (int k = 0; k < 32; ++k)
        acc = fmaf(fmaxf(row[k] + b2[k], 0.f), Wfc[k * 7 + o], acc);
    out[t] = acc;
}

extern "C" void kernel_launch(void* const* d_in, const int* in_sizes, int n_in,
                              void* d_out, int out_size, void* d_ws, size_t ws_size,
                              hipStream_t stream) {
    const float* x   = (const float*)d_in[0];
    const int*   ei  = (const int*)d_in[1];
    const float* W1  = (const float*)d_in[2];
    const float* b1  = (const float*)d_in[3];
    const float* W2  = (const float*)d_in[4];
    const float* b2  = (const float*)d_in[5];
    const float* Wfc = (const float*)d_in[6];
    const float* bfc = (const float*)d_in[7];

    const int n = in_sizes[0] / 288;       // 100000
    const int E = in_sizes[1] / 2;         // 3200000
    const int* src = ei;
    const int* dst = ei + E;
    const int nb = (n + BN - 1) >> BSH;    // 782

    int*   wsI  = (int*)d_ws;
    size_t p = 0;
    int*   bcnt = wsI + p;  p += NBMAX;
    int*   boff = wsI + p;  p += NBMAX;
    int*   bwp  = wsI + p;  p += NBMAX;
    int*   ebuf = wsI + p;  p += (size_t)(E + 4) & ~(size_t)3;
    float* dinv = (float*)(wsI + p);  p += (size_t)(n + 4) & ~(size_t)3;
    float* buf1 = (float*)(wsI + p);  p += (size_t)n * 32;
    float* buf2 = (float*)(wsI + p);
    float* out  = (float*)d_out;

    k_zerob  <<<1, 1024, 0, stream>>>(bcnt);
    k_binhist<<<1024, THREADS, 0, stream>>>(dst, bcnt, E, nb);
    k_binscan<<<1, 1024, 0, stream>>>(bcnt, boff, bwp, nb);
    k_binfill<<<1024, THREADS, 0, stream>>>(src, dst, bwp, ebuf, E);
    k_deg    <<<nb, THREADS, 0, stream>>>(ebuf, boff, bcnt, dinv, n);

    k_gemm1<<<(n + 15) / 16, THREADS, 0, stream>>>(x, W1, dinv, buf1, n);

    k_agg<16><<<nb, THREADS, 0, stream>>>(buf1, ebuf, boff, bcnt, dinv, buf2, n);

    k_gemm2<<<((size_t)n * 32 + THREADS - 1) / THREADS, THREADS, 0, stream>>>(
        buf2, b1, W2, dinv, buf1, n);

    k_agg<32><<<nb, THREADS, 0, stream>>>(buf1, ebuf, boff, bcnt, dinv, buf2, n);

    k_final<<<((size_t)n * 7 + THREADS - 1) / THREADS, THREADS, 0, stream>>>(
        buf2, b2, Wfc, bfc, out, n);
}

// Round 5
// 1173.131 us; speedup vs baseline: 1.6171x; 1.6171x over previous
//
#include <hip/hip_runtime.h>

#define THREADS 256
#define BSH 7
#define BN  128                 // nodes per bucket
#define NBMAX 1024              // max buckets (n <= 131072)
#define NBLK 256                // partition blocks
#define SCAN_WG 1024

// ---------------- pass 1: per-(bucket,block) histogram ----------------
__global__ __launch_bounds__(THREADS) void k_hist(const int* __restrict__ dst,
                                                  int* __restrict__ tbl,
                                                  int E, int nb, int chunk) {
    __shared__ int h[NBMAX];
    for (int i = threadIdx.x; i < NBMAX; i += THREADS) h[i] = 0;
    __syncthreads();
    const int e0 = blockIdx.x * chunk;
    const int e1 = min(E, e0 + chunk);
    for (int e = e0 + threadIdx.x; e < e1; e += THREADS)
        atomicAdd(&h[dst[e] >> BSH], 1);
    __syncthreads();
    for (int b = threadIdx.x; b < nb; b += THREADS)
        tbl[b * NBLK + blockIdx.x] = h[b];          // bucket-major
}

// ---------------- scan of tbl (T = nb*NBLK entries) ----------------
__global__ __launch_bounds__(SCAN_WG) void k_scanA(const int* __restrict__ tbl,
                                                   int* __restrict__ tbl2,
                                                   int* __restrict__ bsum, int T) {
    __shared__ int s[SCAN_WG];
    const int tid = threadIdx.x;
    const int i = blockIdx.x * SCAN_WG + tid;
    int v = (i < T) ? tbl[i] : 0;
    int a = v;
    s[tid] = a; __syncthreads();
    for (int d = 1; d < SCAN_WG; d <<= 1) {
        int add = (tid >= d) ? s[tid - d] : 0;
        __syncthreads();
        a += add; s[tid] = a;
        __syncthreads();
    }
    if (i < T) tbl2[i] = a - v;                     // exclusive
    if (tid == SCAN_WG - 1) bsum[blockIdx.x] = a;
}

__global__ __launch_bounds__(THREADS) void k_scanB(int* __restrict__ bsum, int nbs) {
    __shared__ int s[THREADS];
    const int tid = threadIdx.x;
    int v = (tid < nbs) ? bsum[tid] : 0;
    int a = v;
    s[tid] = a; __syncthreads();
    for (int d = 1; d < THREADS; d <<= 1) {
        int add = (tid >= d) ? s[tid - d] : 0;
        __syncthreads();
        a += add; s[tid] = a;
        __syncthreads();
    }
    if (tid < nbs) bsum[tid] = a - v;
}

__global__ __launch_bounds__(SCAN_WG) void k_scanC(int* __restrict__ tbl2,
                                                   const int* __restrict__ bsum, int T) {
    const int i = blockIdx.x * SCAN_WG + threadIdx.x;
    if (i < T) tbl2[i] += bsum[blockIdx.x];
}

__global__ __launch_bounds__(THREADS) void k_bmeta(const int* __restrict__ tbl2,
                                                   int* __restrict__ boff,
                                                   int* __restrict__ bcnt, int nb, int E) {
    const int b = blockIdx.x * THREADS + threadIdx.x;
    if (b < nb) {
        int s0 = tbl2[(size_t)b * NBLK];
        int s1 = (b + 1 < nb) ? tbl2[(size_t)(b + 1) * NBLK] : E;
        boff[b] = s0; bcnt[b] = s1 - s0;
    }
}

// ---------------- pass 2: private-offset fill (LDS atomics only) ----------------
__global__ __launch_bounds__(THREADS) void k_fill(const int* __restrict__ src,
                                                  const int* __restrict__ dst,
                                                  const int* __restrict__ tbl2,
                                                  int* __restrict__ ebuf,
                                                  int E, int nb, int chunk) {
    __shared__ int wp[NBMAX];
    for (int b = threadIdx.x; b < nb; b += THREADS)
        wp[b] = tbl2[b * NBLK + blockIdx.x];
    __syncthreads();
    const int e0 = blockIdx.x * chunk;
    const int e1 = min(E, e0 + chunk);
    for (int e = e0 + threadIdx.x; e < e1; e += THREADS) {
        int d = dst[e];
        int pos = atomicAdd(&wp[d >> BSH], 1);
        ebuf[pos] = (src[e] << BSH) | (d & (BN - 1));
    }
}

// ---------------- degree -> dinv (per-bucket LDS histogram) ----------------
__global__ __launch_bounds__(THREADS) void k_deg(const int* __restrict__ ebuf,
                                                 const int* __restrict__ boff,
                                                 const int* __restrict__ bcnt,
                                                 float* __restrict__ dinv, int n) {
    __shared__ int h[BN];
    const int b = blockIdx.x, t = threadIdx.x;
    if (t < BN) h[t] = 0;
    __syncthreads();
    const int beg = boff[b], m = bcnt[b];
    for (int j = t; j < m; j += THREADS)
        atomicAdd(&h[ebuf[beg + j] & (BN - 1)], 1);
    __syncthreads();
    if (t < BN) {
        int node = (b << BSH) + t;
        if (node < n) dinv[node] = rsqrtf((float)h[t] + 1.0f);  // +1 self loop
    }
}

// ---------------- GEMM1: xw[i][f] = (x[i] @ W1)[f] * dinv[i] ----------------
__global__ __launch_bounds__(THREADS) void k_gemm1(const float* __restrict__ x,
                                                   const float* __restrict__ W1,
                                                   const float* __restrict__ dinv,
                                                   float* __restrict__ xw, int n) {
    __shared__ float xs[16 * 292];
    __shared__ float wsh[288 * 16];
    const int t = threadIdx.x;
    const int block0 = blockIdx.x * 16;

    for (int i = t; i < 288 * 16; i += THREADS) wsh[i] = W1[i];

    int rows = n - block0; if (rows > 16) rows = 16;
    const float4* x4 = reinterpret_cast<const float4*>(x + (size_t)block0 * 288);
    const int tot4 = rows * 72;
    for (int i = t; i < tot4; i += THREADS) {
        int r = i / 72, c = i - r * 72;
        *reinterpret_cast<float4*>(&xs[r * 292 + c * 4]) = x4[i];
    }
    __syncthreads();

    const int nl = t >> 4, f = t & 15;
    const int row = block0 + nl;
    if (row < n) {
        float acc = 0.f;
        #pragma unroll 8
        for (int k = 0; k < 288; ++k)
            acc = fmaf(xs[nl * 292 + k], wsh[k * 16 + f], acc);
        xw[(size_t)row * 16 + f] = acc * dinv[row];
    }
}

// ---------------- binned LDS push aggregation ----------------
template <int F>
__global__ __launch_bounds__(THREADS) void k_agg(const float* __restrict__ xws,
                                                 const int* __restrict__ ebuf,
                                                 const int* __restrict__ boff,
                                                 const int* __restrict__ bcnt,
                                                 const float* __restrict__ dinv,
                                                 float* __restrict__ out, int n) {
    __shared__ float acc[BN * F];
    const int b = blockIdx.x, t = threadIdx.x;
    const int base = b << BSH;
    constexpr int EP = THREADS / F;
    const int f = t % F, r0 = t / F;

    for (int rr = r0; rr < BN; rr += EP) {
        int node = base + rr;
        acc[rr * F + f] = (node < n) ? xws[(size_t)node * F + f] : 0.f;  // self
    }
    __syncthreads();

    const int beg = boff[b], m = bcnt[b];
    #pragma unroll 4
    for (int j = r0; j < m; j += EP) {
        int ent = ebuf[beg + j];
        int s = ent >> BSH, dl = ent & (BN - 1);
        atomicAdd(&acc[dl * F + f], xws[(size_t)s * F + f]);
    }
    __syncthreads();

    for (int rr = r0; rr < BN; rr += EP) {
        int node = base + rr;
        if (node < n) out[(size_t)node * F + f] = acc[rr * F + f] * dinv[node];
    }
}

// ---------------- GEMM2 ----------------
__global__ __launch_bounds__(THREADS) void k_gemm2(const float* __restrict__ agg1,
                                                   const float* __restrict__ b1,
                                                   const float* __restrict__ W2,
                                                   const float* __restrict__ dinv,
                                                   float* __restrict__ h, int n) {
    int t = blockIdx.x * THREADS + threadIdx.x;
    if (t >= n * 32) return;
    int node = t >> 5, f = t & 31;
    const float* row = agg1 + (size_t)node * 16;
    float acc = 0.f;
    #pragma unroll
    for (int k = 0; k < 16; ++k) {
        float v = fmaxf(row[k] + b1[k], 0.f);
        acc = fmaf(v, W2[k * 32 + f], acc);
    }
    h[t] = acc * dinv[node];
}

// ---------------- final FC ----------------
__global__ __launch_bounds__(THREADS) void k_final(const float* __restrict__ agg2,
                                                   const float* __restrict__ b2,
                                                   const float* __restrict__ Wfc,
                                                   const float* __restrict__ bfc,
                                                   float* __restrict__ out, int n) {
    int t = blockIdx.x * THREADS + threadIdx.x;
    if (t >= n * 7) return;
    int node = t / 7, o = t - node * 7;
    const float* row = agg2 + (size_t)node * 32;
    float acc = bfc[o];
    #pragma unroll
    for (int k = 0; k < 32; ++k)
        acc = fmaf(fmaxf(row[k] + b2[k], 0.f), Wfc[k * 7 + o], acc);
    out[t] = acc;
}

extern "C" void kernel_launch(void* const* d_in, const int* in_sizes, int n_in,
                              void* d_out, int out_size, void* d_ws, size_t ws_size,
                              hipStream_t stream) {
    const float* x   = (const float*)d_in[0];
    const int*   ei  = (const int*)d_in[1];
    const float* W1  = (const float*)d_in[2];
    const float* b1  = (const float*)d_in[3];
    const float* W2  = (const float*)d_in[4];
    const float* b2  = (const float*)d_in[5];
    const float* Wfc = (const float*)d_in[6];
    const float* bfc = (const float*)d_in[7];

    const int n = in_sizes[0] / 288;       // 100000
    const int E = in_sizes[1] / 2;         // 3200000
    const int* src = ei;
    const int* dst = ei + E;
    const int nb = (n + BN - 1) >> BSH;    // 782
    const int T  = nb * NBLK;              // 200192
    const int chunk = (E + NBLK - 1) / NBLK;
    const int nScan = (T + SCAN_WG - 1) / SCAN_WG;   // 196

    int*   wsI  = (int*)d_ws;
    size_t p = 0;
    int*   tbl  = wsI + p;  p += (size_t)T;
    int*   tbl2 = wsI + p;  p += (size_t)T;
    int*   bsum = wsI + p;  p += THREADS;          // nScan <= 256
    int*   boff = wsI + p;  p += NBMAX;
    int*   bcnt = wsI + p;  p += NBMAX;
    int*   ebuf = wsI + p;  p += ((size_t)E + 4) & ~(size_t)3;
    float* dinv = (float*)(wsI + p);  p += ((size_t)n + 4) & ~(size_t)3;
    float* buf1 = (float*)(wsI + p);  p += (size_t)n * 32;
    float* buf2 = (float*)(wsI + p);
    float* out  = (float*)d_out;

    k_hist <<<NBLK, THREADS, 0, stream>>>(dst, tbl, E, nb, chunk);
    k_scanA<<<nScan, SCAN_WG, 0, stream>>>(tbl, tbl2, bsum, T);
    k_scanB<<<1, THREADS, 0, stream>>>(bsum, nScan);
    k_scanC<<<nScan, SCAN_WG, 0, stream>>>(tbl2, bsum, T);
    k_bmeta<<<(nb + THREADS - 1) / THREADS, THREADS, 0, stream>>>(tbl2, boff, bcnt, nb, E);
    k_fill <<<NBLK, THREADS, 0, stream>>>(src, dst, tbl2, ebuf, E, nb, chunk);

    k_deg  <<<nb, THREADS, 0, stream>>>(ebuf, boff, bcnt, dinv, n);

    k_gemm1<<<(n + 15) / 16, THREADS, 0, stream>>>(x, W1, dinv, buf1, n);

    k_agg<16><<<nb, THREADS, 0, stream>>>(buf1, ebuf, boff, bcnt, dinv, buf2, n);

    k_gemm2<<<((size_t)n * 32 + THREADS - 1) / THREADS, THREADS, 0, stream>>>(
        buf2, b1, W2, dinv, buf1, n);

    k_agg<32><<<nb, THREADS, 0, stream>>>(buf1, ebuf, boff, bcnt, dinv, buf2, n);

    k_final<<<((size_t)n * 7 + THREADS - 1) / THREADS, THREADS, 0, stream>>>(
        buf2, b2, Wfc, bfc, out, n);
}

// Round 6
// 806.380 us; speedup vs baseline: 2.3526x; 1.4548x over previous
//
#include <hip/hip_runtime.h>

#define THREADS 256
#define TA 512                  // k_agg block size
#define BSH 7
#define BN  128                 // nodes per bucket
#define NBMAX 1024              // max buckets (n <= 131072)
#define NBLK 256                // partition blocks
#define SCAN_WG 1024
#define PAD 17                  // LDS accumulator row stride (floats)

// ---------------- pass 1: per-(bucket,block) histogram ----------------
__global__ __launch_bounds__(THREADS) void k_hist(const int* __restrict__ dst,
                                                  int* __restrict__ tbl,
                                                  int E, int nb, int chunk) {
    __shared__ int h[NBMAX];
    for (int i = threadIdx.x; i < NBMAX; i += THREADS) h[i] = 0;
    __syncthreads();
    const int e0 = blockIdx.x * chunk;
    const int e1 = min(E, e0 + chunk);
    for (int e = e0 + threadIdx.x; e < e1; e += THREADS)
        atomicAdd(&h[dst[e] >> BSH], 1);
    __syncthreads();
    for (int b = threadIdx.x; b < nb; b += THREADS)
        tbl[b * NBLK + blockIdx.x] = h[b];          // bucket-major
}

// ---------------- scan of tbl (T = nb*NBLK entries) ----------------
__global__ __launch_bounds__(SCAN_WG) void k_scanA(const int* __restrict__ tbl,
                                                   int* __restrict__ tbl2,
                                                   int* __restrict__ bsum, int T) {
    __shared__ int s[SCAN_WG];
    const int tid = threadIdx.x;
    const int i = blockIdx.x * SCAN_WG + tid;
    int v = (i < T) ? tbl[i] : 0;
    int a = v;
    s[tid] = a; __syncthreads();
    for (int d = 1; d < SCAN_WG; d <<= 1) {
        int add = (tid >= d) ? s[tid - d] : 0;
        __syncthreads();
        a += add; s[tid] = a;
        __syncthreads();
    }
    if (i < T) tbl2[i] = a - v;                     // exclusive
    if (tid == SCAN_WG - 1) bsum[blockIdx.x] = a;
}

__global__ __launch_bounds__(THREADS) void k_scanB(int* __restrict__ bsum, int nbs) {
    __shared__ int s[THREADS];
    const int tid = threadIdx.x;
    int v = (tid < nbs) ? bsum[tid] : 0;
    int a = v;
    s[tid] = a; __syncthreads();
    for (int d = 1; d < THREADS; d <<= 1) {
        int add = (tid >= d) ? s[tid - d] : 0;
        __syncthreads();
        a += add; s[tid] = a;
        __syncthreads();
    }
    if (tid < nbs) bsum[tid] = a - v;
}

__global__ __launch_bounds__(SCAN_WG) void k_scanC(int* __restrict__ tbl2,
                                                   const int* __restrict__ bsum, int T) {
    const int i = blockIdx.x * SCAN_WG + threadIdx.x;
    if (i < T) tbl2[i] += bsum[blockIdx.x];
}

__global__ __launch_bounds__(THREADS) void k_bmeta(const int* __restrict__ tbl2,
                                                   int* __restrict__ boff,
                                                   int* __restrict__ bcnt, int nb, int E) {
    const int b = blockIdx.x * THREADS + threadIdx.x;
    if (b < nb) {
        int s0 = tbl2[(size_t)b * NBLK];
        int s1 = (b + 1 < nb) ? tbl2[(size_t)(b + 1) * NBLK] : E;
        boff[b] = s0; bcnt[b] = s1 - s0;
    }
}

// ---------------- pass 2: private-offset fill (LDS atomics only) ----------------
__global__ __launch_bounds__(THREADS) void k_fill(const int* __restrict__ src,
                                                  const int* __restrict__ dst,
                                                  const int* __restrict__ tbl2,
                                                  int* __restrict__ ebuf,
                                                  int E, int nb, int chunk) {
    __shared__ int wp[NBMAX];
    for (int b = threadIdx.x; b < nb; b += THREADS)
        wp[b] = tbl2[b * NBLK + blockIdx.x];
    __syncthreads();
    const int e0 = blockIdx.x * chunk;
    const int e1 = min(E, e0 + chunk);
    for (int e = e0 + threadIdx.x; e < e1; e += THREADS) {
        int d = dst[e];
        int pos = atomicAdd(&wp[d >> BSH], 1);
        ebuf[pos] = (src[e] << BSH) | (d & (BN - 1));
    }
}

// ---------------- degree -> dinv (per-bucket LDS histogram) ----------------
__global__ __launch_bounds__(THREADS) void k_deg(const int* __restrict__ ebuf,
                                                 const int* __restrict__ boff,
                                                 const int* __restrict__ bcnt,
                                                 float* __restrict__ dinv, int n) {
    __shared__ int h[BN];
    const int b = blockIdx.x, t = threadIdx.x;
    if (t < BN) h[t] = 0;
    __syncthreads();
    const int beg = boff[b], m = bcnt[b];
    for (int j = t; j < m; j += THREADS)
        atomicAdd(&h[ebuf[beg + j] & (BN - 1)], 1);
    __syncthreads();
    if (t < BN) {
        int node = (b << BSH) + t;
        if (node < n) dinv[node] = rsqrtf((float)h[t] + 1.0f);  // +1 self loop
    }
}

// ---------------- GEMM1: xw[i][f] = (x[i] @ W1)[f] * dinv[i] ----------------
__global__ __launch_bounds__(THREADS) void k_gemm1(const float* __restrict__ x,
                                                   const float* __restrict__ W1,
                                                   const float* __restrict__ dinv,
                                                   float* __restrict__ xw, int n) {
    __shared__ float xs[16 * 292];
    __shared__ float wsh[288 * 16];
    const int t = threadIdx.x;
    const int block0 = blockIdx.x * 16;

    for (int i = t; i < 288 * 16; i += THREADS) wsh[i] = W1[i];

    int rows = n - block0; if (rows > 16) rows = 16;
    const float4* x4 = reinterpret_cast<const float4*>(x + (size_t)block0 * 288);
    const int tot4 = rows * 72;
    for (int i = t; i < tot4; i += THREADS) {
        int r = i / 72, c = i - r * 72;
        *reinterpret_cast<float4*>(&xs[r * 292 + c * 4]) = x4[i];
    }
    __syncthreads();

    const int nl = t >> 4, f = t & 15;
    const int row = block0 + nl;
    if (row < n) {
        float acc = 0.f;
        #pragma unroll 8
        for (int k = 0; k < 288; ++k)
            acc = fmaf(xs[nl * 292 + k], wsh[k * 16 + f], acc);
        xw[(size_t)row * 16 + f] = acc * dinv[row];
    }
}

// ---------------- binned LDS push aggregation, F=16, fused epilogue ----------------
// input rows pre-scaled by dinv[src]; self-loop = own row.
// EPI==1: out = relu(acc*dinv + bias[f]) * dinv   (layer-1 epilogue, pre-scaled for next agg)
// EPI==0: out = acc*dinv                           (plain segsum result)
template <int EPI>
__global__ __launch_bounds__(TA) void k_agg16(const float* __restrict__ xws,
                                              const int* __restrict__ ebuf,
                                              const int* __restrict__ boff,
                                              const int* __restrict__ bcnt,
                                              const float* __restrict__ dinv,
                                              const float* __restrict__ bias,
                                              float* __restrict__ out, int n) {
    __shared__ float acc[BN * PAD];
    const int b = blockIdx.x, t = threadIdx.x;
    const int base = b << BSH;
    constexpr int EP = TA / 16;            // 32 entries per iteration
    const int f = t & 15, r0 = t >> 4;

    #pragma unroll
    for (int rr = r0; rr < BN; rr += EP) {
        int node = base + rr;
        acc[rr * PAD + f] = (node < n) ? xws[(size_t)node * 16 + f] : 0.f;  // self
    }
    __syncthreads();

    const int beg = boff[b], m = bcnt[b];
    #pragma unroll 8
    for (int j = r0; j < m; j += EP) {
        int ent = ebuf[beg + j];
        int s = ent >> BSH, dl = ent & (BN - 1);
        atomicAdd(&acc[dl * PAD + f], xws[(size_t)s * 16 + f]);
    }
    __syncthreads();

    #pragma unroll
    for (int rr = r0; rr < BN; rr += EP) {
        int node = base + rr;
        if (node < n) {
            float dv = dinv[node];
            float v = acc[rr * PAD + f] * dv;
            if (EPI) v = fmaxf(v + bias[f], 0.f) * dv;
            out[(size_t)node * 16 + f] = v;
        }
    }
}

// ---------------- fused head: out = relu(s2 @ W2 + b2) @ Wfc + bfc ----------------
__global__ __launch_bounds__(THREADS) void k_head(const float* __restrict__ s2,
                                                  const float* __restrict__ W2,
                                                  const float* __restrict__ b2,
                                                  const float* __restrict__ Wfc,
                                                  const float* __restrict__ bfc,
                                                  float* __restrict__ out, int n) {
    __shared__ float w2[16 * 32];
    __shared__ float wf[32 * 7];
    __shared__ float bb2[32];
    __shared__ float bbf[7];
    const int t = threadIdx.x;
    for (int i = t; i < 16 * 32; i += THREADS) w2[i] = W2[i];
    for (int i = t; i < 32 * 7; i += THREADS) wf[i] = Wfc[i];
    if (t < 32) bb2[t] = b2[t];
    if (t < 7)  bbf[t] = bfc[t];
    __syncthreads();

    const int i = blockIdx.x * THREADS + t;
    if (i >= n) return;

    float v[16];
    const float4* p = reinterpret_cast<const float4*>(s2 + (size_t)i * 16);
    #pragma unroll
    for (int q = 0; q < 4; ++q) {
        float4 x4 = p[q];
        v[q * 4 + 0] = x4.x; v[q * 4 + 1] = x4.y; v[q * 4 + 2] = x4.z; v[q * 4 + 3] = x4.w;
    }
    float h[32];
    #pragma unroll
    for (int o = 0; o < 32; ++o) {
        float a = bb2[o];
        #pragma unroll
        for (int k = 0; k < 16; ++k) a = fmaf(v[k], w2[k * 32 + o], a);
        h[o] = fmaxf(a, 0.f);
    }
    #pragma unroll
    for (int o = 0; o < 7; ++o) {
        float a = bbf[o];
        #pragma unroll
        for (int k = 0; k < 32; ++k) a = fmaf(h[k], wf[k * 7 + o], a);
        out[(size_t)i * 7 + o] = a;
    }
}

extern "C" void kernel_launch(void* const* d_in, const int* in_sizes, int n_in,
                              void* d_out, int out_size, void* d_ws, size_t ws_size,
                              hipStream_t stream) {
    const float* x   = (const float*)d_in[0];
    const int*   ei  = (const int*)d_in[1];
    const float* W1  = (const float*)d_in[2];
    const float* b1  = (const float*)d_in[3];
    const float* W2  = (const float*)d_in[4];
    const float* b2  = (const float*)d_in[5];
    const float* Wfc = (const float*)d_in[6];
    const float* bfc = (const float*)d_in[7];

    const int n = in_sizes[0] / 288;       // 100000
    const int E = in_sizes[1] / 2;         // 3200000
    const int* src = ei;
    const int* dst = ei + E;
    const int nb = (n + BN - 1) >> BSH;    // 782
    const int T  = nb * NBLK;              // 200192
    const int chunk = (E + NBLK - 1) / NBLK;
    const int nScan = (T + SCAN_WG - 1) / SCAN_WG;   // 196

    int*   wsI  = (int*)d_ws;
    size_t p = 0;
    int*   tbl  = wsI + p;  p += (size_t)T;
    int*   tbl2 = wsI + p;  p += (size_t)T;
    int*   bsum = wsI + p;  p += THREADS;          // nScan <= 256
    int*   boff = wsI + p;  p += NBMAX;
    int*   bcnt = wsI + p;  p += NBMAX;
    int*   ebuf = wsI + p;  p += ((size_t)E + 4) & ~(size_t)3;
    float* dinv = (float*)(wsI + p);  p += ((size_t)n + 4) & ~(size_t)3;
    float* buf1 = (float*)(wsI + p);  p += (size_t)n * 16;   // xw / s2
    float* buf2 = (float*)(wsI + p);                          // t1
    float* out  = (float*)d_out;

    k_hist <<<NBLK, THREADS, 0, stream>>>(dst, tbl, E, nb, chunk);
    k_scanA<<<nScan, SCAN_WG, 0, stream>>>(tbl, tbl2, bsum, T);
    k_scanB<<<1, THREADS, 0, stream>>>(bsum, nScan);
    k_scanC<<<nScan, SCAN_WG, 0, stream>>>(tbl2, bsum, T);
    k_bmeta<<<(nb + THREADS - 1) / THREADS, THREADS, 0, stream>>>(tbl2, boff, bcnt, nb, E);
    k_fill <<<NBLK, THREADS, 0, stream>>>(src, dst, tbl2, ebuf, E, nb, chunk);

    k_deg  <<<nb, THREADS, 0, stream>>>(ebuf, boff, bcnt, dinv, n);

    k_gemm1<<<(n + 15) / 16, THREADS, 0, stream>>>(x, W1, dinv, buf1, n);

    // layer-1 aggregation + fused relu/bias epilogue (pre-scaled for layer 2)
    k_agg16<1><<<nb, TA, 0, stream>>>(buf1, ebuf, boff, bcnt, dinv, b1, buf2, n);

    // layer-2 aggregation on 16-wide h1 (aggregate-before-transform)
    k_agg16<0><<<nb, TA, 0, stream>>>(buf2, ebuf, boff, bcnt, dinv, nullptr, buf1, n);

    // fused: relu(s2 @ W2 + b2) @ Wfc + bfc
    k_head <<<(n + THREADS - 1) / THREADS, THREADS, 0, stream>>>(
        buf1, W2, b2, Wfc, bfc, out, n);
}